// Round 8
// baseline (8043.460 us; speedup 1.0000x reference)
//
#include <hip/hip_runtime.h>

#define NSTEP 512
#define EDIM  512
#define REC   2048
#define NB    64
#define KSEL  819
#define KC    8       // K chunks of 256 (kc = bid & 7)
#define ZCH   256     // K per block
#define AP    264     // padded k-stride (u16) for LDS tiles
#define CSTR  16896   // 64*AP: component stride inside LDS tiles
#define WITC  1048576 // u16 elems per WiT component (2048*512)

typedef unsigned short u16;
typedef __bf16 bf16x8 __attribute__((ext_vector_type(8)));
typedef float  f32x4  __attribute__((ext_vector_type(4)));
typedef unsigned long long ull;

static __device__ __forceinline__ f32x4 mfma16(bf16x8 a, bf16x8 b, f32x4 c) {
    return __builtin_amdgcn_mfma_f32_16x16x32_bf16(a, b, c, 0, 0, 0);
}

// fp32 -> 2 bf16 components (hi, lo): ~17 mantissa bits
static __device__ __forceinline__ void split2(float v, u16& c0, u16& c1) {
    __bf16 b0 = (__bf16)v;
    __bf16 b1 = (__bf16)(v - (float)b0);
    c0 = __builtin_bit_cast(u16, b0);
    c1 = __builtin_bit_cast(u16, b1);
}

// ---- agent-scope (sc1) coherent helpers — compiler-tracked ----
static __device__ __forceinline__ void cstore4f(float* p, float v) {
    __hip_atomic_store((unsigned*)p, __float_as_uint(v), __ATOMIC_RELAXED, __HIP_MEMORY_SCOPE_AGENT);
}
static __device__ __forceinline__ void cstore4u(unsigned* p, unsigned v) {
    __hip_atomic_store(p, v, __ATOMIC_RELAXED, __HIP_MEMORY_SCOPE_AGENT);
}
static __device__ __forceinline__ unsigned cload4u(const unsigned* p) {
    return __hip_atomic_load(p, __ATOMIC_RELAXED, __HIP_MEMORY_SCOPE_AGENT);
}
static __device__ __forceinline__ void cstore8u(void* p, ull v) {
    __hip_atomic_store((ull*)p, v, __ATOMIC_RELAXED, __HIP_MEMORY_SCOPE_AGENT);
}
static __device__ __forceinline__ ull cload8u(const void* p) {
    return __hip_atomic_load((const ull*)p, __ATOMIC_RELAXED, __HIP_MEMORY_SCOPE_AGENT);
}
static __device__ __forceinline__ float2 cload8f(const float* p) {
    ull u = cload8u(p);
    float2 v; __builtin_memcpy(&v, &u, 8);
    return v;
}

// ---------------------------------------------------------------------------
// Sync objects. bar layout (uints):
//   arriveA[0..255] | releaseA[1024+g*32]      — leader barrier (init only)
//   gcnt[g] at [1536 + g*32], g<4             — per-16-row r-ready counters
//   ncnt[nc] at [2048 + nc*32], nc<32         — per-column-chunk z-ready
// Main loop is BARRIER-FREE: r-visibility via gcnt (16-fan-in/line, set by
// each B block after its r stores drain; observed counter => stores visible
// at MALL, same reasoning as all prior barriers), z-visibility via ncnt
// (8-fan-in, R6-proven). The znxt-zero hazard is gone: each phase-B block
// zeroes its OWN z row right after reading it; GEMM(t+2) adds into that
// parity only after gcnt(t+1), which program-order-follows the zeroing.
// ---------------------------------------------------------------------------
__device__ __forceinline__ void gbarA(unsigned* bar, int bid, int tid,
                                      unsigned gen, bool wait)
{
    __syncthreads();                               // drain block stores
    if (tid == 0) cstore4u(&bar[bid], gen);        // arrive
    if (bid == 0 && tid < 64) {                    // leader wave: parallel poll
        const ull* sl = (const ull*)bar;           // 128 ulls = 256 slots
        for (;;) {
            const ull v0 = cload8u(&sl[tid * 2]);
            const ull v1 = cload8u(&sl[tid * 2 + 1]);
            const bool ok = ((unsigned)v0 >= gen) && ((unsigned)(v0 >> 32) >= gen)
                         && ((unsigned)v1 >= gen) && ((unsigned)(v1 >> 32) >= gen);
            if (__all(ok)) break;
            __builtin_amdgcn_s_sleep(1);
        }
        if (tid < 16) cstore4u(&bar[1024 + tid * 32], gen);
    }
    if (wait) {
        if (tid == 0) {
            const int g = bid >> 4;
            while (cload4u(&bar[1024 + g * 32]) < gen)
                __builtin_amdgcn_s_sleep(1);
            __asm__ volatile("" ::: "memory");
        }
        __syncthreads();
    }
}

// ---------------------------------------------------------------------------
// Persistent kernel: 256 blocks x 512 threads. R6 structure (z atomics into
// zb ping-pong, rTu split state, per-nc ncnt, MFMA Y precompute,
// candidate-list tail) with the main-loop leader barB REMOVED:
//   - stage(t) gated on gcnt[g] >= 16*t  (r(t-1) ready, 4 groups of 16 rows)
//   - phase-B(t) zeroes its z row after reading (reader-zeroing)
//   - phase-B(t) ends with syncthreads + gcnt[b>>4] += 1
// Init gens: 1 = WiT done, 2 = Y+init done. ncnt target: 8*(t+1).
// ---------------------------------------------------------------------------
__global__ __launch_bounds__(512, 1)
void rnn_persistent(const float* __restrict__ x, const float* __restrict__ Wi,
                    const float* __restrict__ Wr, float* __restrict__ out,
                    u16* __restrict__ rTu, float* __restrict__ zb,
                    u16* __restrict__ Ybf, u16* __restrict__ WiTu,
                    unsigned* __restrict__ bar)
{
    extern __shared__ __align__(16) char smem[];
    u16* WrSu = (u16*)smem;                         // + c*CSTR
    u16* aSu  = (u16*)(smem + 67584);               // + c*CSTR
    // transpose view (aliases WrSu region, used only pre-gen1)
    float* tp = (float*)smem;                       // [64][65] 16.6 KB
    // phase-B views (alias aS region)
    unsigned*      kS    = (unsigned*)(smem + 67584);            // [2048] 8 KB
    unsigned char* selS  = (unsigned char*)(smem + 67584 + 8192);// 2 KB
    unsigned*      hist  = (unsigned*)(smem + 67584 + 10240);    // [8][256] 8 KB
    __shared__ unsigned s_byte, s_newrem, s_cnteq;
    __shared__ float red[8];

    const int bid = blockIdx.x;
    const int tid = threadIdx.x;
    const int kc = bid & 7, nc = bid >> 3;
    const int n0 = nc * 64, kcbase = kc * ZCH;
    const int wid = tid >> 6, lane = tid & 63;
    const int q = lane >> 4, l16 = lane & 15;
    const int Moff = (wid & 3) * 16, Npair = wid >> 2;
    const bool isB = (bid < NB);
    unsigned* ncnt = &bar[2048];                    // + nc*32
    unsigned* gcnt = &bar[1536];                    // + g*32, g<4

    // ============ Phase 0: split-Wi^T transpose (one 64x64 tile/block) ======
    {
        const int jt = bid & 31, et = bid >> 5;
        const int j0 = jt * 64, e0 = et * 64;
        const int rr = tid >> 6, ln = tid & 63;
#pragma unroll
        for (int k = 0; k < 8; ++k) {
            const int r = k * 8 + rr;
            tp[r * 65 + ln] = Wi[(long long)(e0 + r) * REC + j0 + ln];
        }
        __syncthreads();
        const int c = tid >> 3, e8 = (tid & 7) * 8;
        u16 h[8], l[8];
#pragma unroll
        for (int i = 0; i < 8; ++i) split2(tp[(e8 + i) * 65 + c], h[i], l[i]);
        ull ph0, ph1, pl0, pl1;
        __builtin_memcpy(&ph0, &h[0], 8); __builtin_memcpy(&ph1, &h[4], 8);
        __builtin_memcpy(&pl0, &l[0], 8); __builtin_memcpy(&pl1, &l[4], 8);
        const long long bI = (long long)(j0 + c) * 512 + e0 + e8;
        cstore8u(&WiTu[bI], ph0);        cstore8u(&WiTu[bI + 4], ph1);
        cstore8u(&WiTu[WITC + bI], pl0); cstore8u(&WiTu[WITC + bI + 4], pl1);
    }
    gbarA(bar, bid, tid, 1u, true);

    // ============ Phase 1: Y[t][b][j] = (x_t @ Wi) via split-bf16 MFMA ======
    {
        const int t0 = bid * 2;
        for (int jc = 0; jc < 32; ++jc) {
            const int j0y = jc * 64;
            f32x4 aY[2][2];
#pragma unroll
            for (int tt = 0; tt < 2; ++tt)
#pragma unroll
                for (int i = 0; i < 2; ++i) aY[tt][i] = (f32x4){0,0,0,0};
            for (int kc2 = 0; kc2 < 2; ++kc2) {
                __syncthreads();                    // prior GEMM reads done
                // ---- stage B: WiT[j0y..+64][kc2*256..+256], both comps ----
#pragma unroll
                for (int i = 0; i < 8; ++i) {
                    const int chunk = i * 512 + tid;        // 4096 x 16B
                    const int cc = chunk >> 11;
                    const int jj = (chunk & 2047) >> 5;
                    const int e8 = chunk & 31;
                    const u16* src = WiTu + (long long)cc * WITC
                                   + (long long)(j0y + jj) * 512 + kc2 * 256 + e8 * 8;
                    const ull w0 = *(const ull*)src;
                    const ull w1 = *(const ull*)(src + 4);
                    u16* dst = WrSu + cc * CSTR + jj * AP + e8 * 8;
                    *(ull*)dst = w0;
                    *(ull*)(dst + 4) = w1;
                }
#pragma unroll
                for (int tt = 0; tt < 2; ++tt) {
                    __syncthreads();                // B staged / prev GEMM done
                    // ---- stage A: x[t][b][kc2*256..+256] split ----
#pragma unroll
                    for (int it = 0; it < 8; ++it) {
                        const int b = it * 8 + wid;
                        const float4 v = *(const float4*)(x
                            + ((long long)b * NSTEP + (t0 + tt)) * EDIM
                            + kc2 * 256 + lane * 4);
                        u16 hh[4], ll[4];
                        split2(v.x, hh[0], ll[0]); split2(v.y, hh[1], ll[1]);
                        split2(v.z, hh[2], ll[2]); split2(v.w, hh[3], ll[3]);
                        ull ph, pl;
                        __builtin_memcpy(&ph, hh, 8); __builtin_memcpy(&pl, ll, 8);
                        *(ull*)&aSu[b * AP + lane * 4] = ph;
                        *(ull*)&aSu[CSTR + b * AP + lane * 4] = pl;
                    }
                    __syncthreads();
                    f32x4 a0 = aY[tt][0], a1 = aY[tt][1];
#pragma unroll
                    for (int ks = 0; ks < 8; ++ks) {
                        const int kk = ks * 32 + q * 8;
                        const u16* ap = aSu + (Moff + l16) * AP + kk;
                        bf16x8 A0 = *(const bf16x8*)(ap);
                        bf16x8 A1 = *(const bf16x8*)(ap + CSTR);
                        const u16* bp0 = WrSu + (Npair * 32 + l16) * AP + kk;
                        bf16x8 B00 = *(const bf16x8*)(bp0);
                        bf16x8 B01 = *(const bf16x8*)(bp0 + CSTR);
                        const u16* bp1 = bp0 + 16 * AP;
                        bf16x8 B10 = *(const bf16x8*)(bp1);
                        bf16x8 B11 = *(const bf16x8*)(bp1 + CSTR);
                        a0 = mfma16(A0, B00, a0);
                        a1 = mfma16(A0, B10, a1);
                        a0 = mfma16(A0, B01, a0);
                        a1 = mfma16(A0, B11, a1);
                        a0 = mfma16(A1, B00, a0);
                        a1 = mfma16(A1, B10, a1);
                    }
                    aY[tt][0] = a0; aY[tt][1] = a1;
                }
            }
            // ---- epilogue: bf16-round, lane-pair pack, agent 4B stores ----
            const int jb = j0y + Npair * 32 + l16;
#pragma unroll
            for (int tt = 0; tt < 2; ++tt)
#pragma unroll
                for (int i = 0; i < 4; ++i) {
                    const int row = Moff + q * 4 + i;
                    const unsigned w0 = (unsigned)__builtin_bit_cast(u16, (__bf16)((float*)&aY[tt][0])[i]);
                    const unsigned w1 = (unsigned)__builtin_bit_cast(u16, (__bf16)((float*)&aY[tt][1])[i]);
                    const unsigned o0 = (unsigned)__shfl_xor((int)w0, 1);
                    const unsigned o1 = (unsigned)__shfl_xor((int)w1, 1);
                    if ((lane & 1) == 0) {
                        const long long yb = ((long long)(t0 + tt) * 64 + row) * REC + jb;
                        cstore4u((unsigned*)&Ybf[yb],      w0 | (o0 << 16));
                        cstore4u((unsigned*)&Ybf[yb + 16], w1 | (o1 << 16));
                    }
                }
        }
    }
    // ---- init: zero r slot (512 KB) and BOTH zb parities (1 MB) ----
    {
        const int g = bid * 512 + tid;                  // 0..131071
        if (g < 65536) cstore8u(rTu + (long long)g * 4, 0ull);
        cstore4f(zb + g, 0.f);
        cstore4f(zb + 131072 + g, 0.f);
    }
    gbarA(bar, bid, tid, 2u, true);

    // ================= one-time: stage + split Wr tile into LDS =============
    {
        for (int it = 0; it < 32; ++it) {
            const int row = it * 8 + wid;
            const int col = lane;
            const float v = Wr[(long long)(kcbase + row) * REC + n0 + col];
            u16 s0, s1; split2(v, s0, s1);
            const int base = col * AP + row;
            WrSu[base] = s0;
            WrSu[CSTR + base] = s1;
        }
        __syncthreads();
    }

    // ================= main recurrence (barrier-free) =======================
    const int hw = tid >> 5, hl = tid & 31;
    for (int t = 0; t < NSTEP; ++t) {
        float* zcur = zb + (size_t)(t & 1) * 131072;
        // ---- wait r(t-1): 4 per-group counters (t=0 target 0, trivially ok)
        if (tid < 4) {
            const unsigned tgt = 16u * (unsigned)t;
            while (cload4u(&gcnt[tid * 32]) < tgt) __builtin_amdgcn_s_sleep(1);
        }
        __asm__ volatile("" ::: "memory");
        __syncthreads();
        // ---- stage aS: 2 comps x 64 b x 256 k, sc1 8B ----
        {
            ull va[8], vbv[8];
#pragma unroll
            for (int i = 0; i < 8; ++i) {
                const int c = i >> 2;
                const int b = (i & 3) * 16 + hw;
                const u16* src = rTu + (long long)c * 131072 + (long long)b * REC + kcbase + hl * 8;
                va[i] = cload8u(src);
                vbv[i] = cload8u(src + 4);
            }
#pragma unroll
            for (int i = 0; i < 8; ++i) {
                const int c = i >> 2;
                const int b = (i & 3) * 16 + hw;
                u16* dst = aSu + c * CSTR + b * AP + hl * 8;
                *(ull*)dst = va[i];
                *(ull*)(dst + 4) = vbv[i];
            }
        }
        __syncthreads();

        // Y prefetch for phase B — issued early, completes under GEMM
        ushort4 yv;
        if (isB) yv = *(const ushort4*)&Ybf[((long long)t * 64 + bid) * REC + tid * 4];

        // ---- z tile: 3-pass split-bf16 MFMA, K=256 ----
        f32x4 acc0 = {0,0,0,0}, acc1 = {0,0,0,0};
#pragma unroll
        for (int ks = 0; ks < 8; ++ks) {
            const int kk = ks * 32 + q * 8;
            const u16* ap = aSu + (Moff + l16) * AP + kk;
            bf16x8 A0 = *(const bf16x8*)(ap);
            bf16x8 A1 = *(const bf16x8*)(ap + CSTR);
            const u16* bp0 = WrSu + (Npair * 32 + l16) * AP + kk;
            bf16x8 B00 = *(const bf16x8*)(bp0);
            bf16x8 B01 = *(const bf16x8*)(bp0 + CSTR);
            const u16* bp1 = bp0 + 16 * AP;
            bf16x8 B10 = *(const bf16x8*)(bp1);
            bf16x8 B11 = *(const bf16x8*)(bp1 + CSTR);
            acc0 = mfma16(A0, B00, acc0);
            acc1 = mfma16(A0, B10, acc1);
            acc0 = mfma16(A0, B01, acc0);
            acc1 = mfma16(A0, B11, acc1);
            acc0 = mfma16(A1, B00, acc0);
            acc1 = mfma16(A1, B10, acc1);
        }
        // ---- accumulate into z via HW f32 atomics ----
        {
            const int colA = n0 + Npair * 32 + l16;
#pragma unroll
            for (int i = 0; i < 4; ++i) {
                float* zp = zcur + (long long)(Moff + q * 4 + i) * REC + colA;
                unsafeAtomicAdd(zp,      ((float*)&acc0)[i]);
                unsafeAtomicAdd(zp + 16, ((float*)&acc1)[i]);
            }
        }
        // ---- per-nc arrival: syncthreads drains z atomics, then 1 add ----
        __syncthreads();
        if (tid == 0) atomicAdd(&ncnt[nc << 5], 1u);

        // ================= phase B: blocks 0..63, one batch row each ========
        if (isB) {
            const int b = bid;
            const int j0 = tid * 4;
            // wait only for the 8 kc-blocks of THIS thread's column chunk
            {
                const unsigned tgt = 8u * (unsigned)(t + 1);
                const unsigned* myc = &ncnt[(tid >> 4) << 5];
                while (cload4u(myc) < tgt) __builtin_amdgcn_s_sleep(1);
                __asm__ volatile("" ::: "memory");
            }
            float zs[4];
            {
                float* zp = zcur + (long long)b * REC + j0;
                const float2 u0 = cload8f(zp);
                const float2 u1 = cload8f(zp + 2);
                zs[0] = u0.x; zs[1] = u0.y; zs[2] = u1.x; zs[3] = u1.y;
                __asm__ volatile("" ::: "memory");   // loads before zeroing
                cstore8u(zp, 0ull);                  // reader zeroes its row:
                cstore8u(zp + 2, 0ull);              // replaces znxt zeroing
            }
            unsigned kv[4];
#pragma unroll
            for (int s = 0; s < 4; ++s) {
                const unsigned u = __float_as_uint(zs[s]);
                kv[s] = (u & 0x80000000u) ? ~u : (u | 0x80000000u);
            }
            // ---- radix select w/ early exit + candidate-list tail ----
            unsigned* hw_ = hist + wid * 256;
            unsigned prefix = 0, remaining = KSEL;
            int done = 0;
            unsigned char sel[4];
            int sel_set = 0;
            for (int byte = 3; byte >= 0 && !done; --byte) {
                {
                    uint4 zz = {0u, 0u, 0u, 0u};
                    *(uint4*)&hw_[lane * 4] = zz;
                }
                const int shift = byte * 8;
                const unsigned pmask = (byte == 3) ? 0u : (0xFFFFFFFFu << (shift + 8));
#pragma unroll
                for (int s = 0; s < 4; ++s) {
                    if ((kv[s] & pmask) == prefix)
                        atomicAdd(&hw_[(kv[s] >> shift) & 255u], 1u);
                }
                __syncthreads();
                if (tid < 64) {   // wave 0: combine 8 copies + suffix scan
                    unsigned c0 = 0, c1 = 0, c2 = 0, c3 = 0;
#pragma unroll
                    for (int w = 0; w < 8; ++w) {
                        const uint4 hv = *(const uint4*)&hist[w * 256 + tid * 4];
                        c0 += hv.x; c1 += hv.y; c2 += hv.z; c3 += hv.w;
                    }
                    const unsigned tot = c0 + c1 + c2 + c3;
                    unsigned suf = tot;
#pragma unroll
                    for (int st = 1; st < 64; st <<= 1) {
                        unsigned o = __shfl_down(suf, (unsigned)st);
                        if (tid + st >= 64) o = 0u;
                        suf += o;
                    }
                    unsigned S[5];
                    S[0] = suf; S[1] = suf - c0; S[2] = suf - c0 - c1;
                    S[3] = suf - c0 - c1 - c2; S[4] = suf - tot;
                    const unsigned cc[4] = {c0, c1, c2, c3};
#pragma unroll
                    for (int qq = 0; qq < 4; ++qq) {
                        if (S[qq] >= remaining && S[qq + 1] < remaining) {
                            s_byte = (unsigned)(tid * 4 + qq);
                            s_newrem = remaining - S[qq + 1];
                            s_cnteq = cc[qq];
                        }
                    }
                }
                __syncthreads();
                prefix |= (s_byte << shift);
                remaining = s_newrem;
                if (remaining == s_cnteq) { done = 1; continue; }
                // ---- candidate-list tail: pivot bucket small -> rank directly
                if (s_cnteq <= 64u) {
                    const unsigned maskk = 0xFFFFFFFFu << shift;
                    if (tid == 0) kS[128] = 0u;
                    *(unsigned*)&selS[j0] = 0u;
                    __syncthreads();
#pragma unroll
                    for (int s = 0; s < 4; ++s) {
                        if ((kv[s] & maskk) == prefix) {
                            const unsigned p = atomicAdd(&kS[128], 1u);
                            kS[p] = kv[s];
                            kS[64 + p] = (unsigned)(j0 + s);
                        }
                    }
                    __syncthreads();
                    if (tid < 64) {
                        const unsigned cnt = kS[128];
                        if ((unsigned)lane < cnt) {
                            const unsigned myK = kS[lane];
                            const unsigned myI = kS[64 + lane];
                            unsigned rank = 0;
                            for (unsigned j = 0; j < cnt; ++j) {
                                const unsigned bk = kS[j], bi = kS[64 + j];
                                if (bk > myK || (bk == myK && bi < myI)) ++rank;
                            }
                            if (rank < remaining) selS[myI] = 1;
                        }
                    }
                    __syncthreads();
#pragma unroll
                    for (int s = 0; s < 4; ++s) {
                        const unsigned m = kv[s] & maskk;
                        sel[s] = (m > prefix) ? 1 : ((m == prefix) ? selS[j0 + s] : 0);
                    }
                    sel_set = 1;
                    break;
                }
            }
            if (!sel_set) {
                if (done) {
#pragma unroll
                    for (int s = 0; s < 4; ++s)
                        sel[s] = (kv[s] >= prefix) ? 1 : 0;
                } else {
                    // tie at exact threshold with >64 dups (step 0: all-zero z).
                    *(uint4*)&kS[j0] = *(uint4*)kv;
                    __syncthreads();
                    if (tid == 0) {
                        unsigned rem = remaining;
                        const unsigned T = prefix;
                        for (int j = 0; j < REC; ++j) {
                            const unsigned k = kS[j];
                            unsigned char sl = 0;
                            if (k > T) sl = 1;
                            else if (k == T && rem > 0u) { sl = 1; --rem; }
                            selS[j] = sl;
                        }
                    }
                    __syncthreads();
#pragma unroll
                    for (int s = 0; s < 4; ++s) sel[s] = selS[j0 + s];
                }
            }
            // ---- r_new = tanh(y + masked z), row-normalize ----
            float rn[4]; float ss = 0.f;
            const u16 ya[4] = {yv.x, yv.y, yv.z, yv.w};
#pragma unroll
            for (int s = 0; s < 4; ++s) {
                const float y = __uint_as_float(((unsigned)ya[s]) << 16);
                const float v = y + (sel[s] ? zs[s] : 0.f);
                const float th = tanhf(v);
                rn[s] = th; ss += th * th;
            }
#pragma unroll
            for (int off = 32; off > 0; off >>= 1)
                ss += __shfl_down(ss, (unsigned)off);
            if (lane == 0) red[wid] = ss;
            __syncthreads();
            float a = 0.f;
#pragma unroll
            for (int i = 0; i < 8; ++i) a += red[i];
            const float inv = 1.0f / (sqrtf(a) + 1e-6f);
            u16 o0[4], o1[4];
            float4 ov;
#pragma unroll
            for (int s = 0; s < 4; ++s) {
                const float v = rn[s] * inv;
                split2(v, o0[s], o1[s]);
                ((float*)&ov)[s] = v;
            }
            ull p0, p1;
            __builtin_memcpy(&p0, o0, 8); __builtin_memcpy(&p1, o1, 8);
            cstore8u(rTu + (long long)b * REC + j0, p0);
            cstore8u(rTu + 131072 + (long long)b * REC + j0, p1);
            if (t == NSTEP - 1)
                *(float4*)&out[(long long)b * REC + j0] = ov;
            // ---- r ready: drain stores, then 1 add to this row's group ----
            __syncthreads();
            if (tid == 0) atomicAdd(&gcnt[(b >> 4) * 32], 1u);
        }
    }
}

// ---------------------------------------------------------------------------
extern "C" void kernel_launch(void* const* d_in, const int* in_sizes, int n_in,
                              void* d_out, int out_size, void* d_ws, size_t ws_size,
                              hipStream_t stream)
{
    const float* x   = (const float*)d_in[0];   // [64][512][512]
    const float* Win = (const float*)d_in[1];   // [512][2048]
    const float* Wr  = (const float*)d_in[2];   // [2048][2048]
    float* out = (float*)d_out;                 // [64][2048]

    char* ws = (char*)d_ws;
    const size_t BAR = 16384;                   // bar slots + gcnt + ncnt
    unsigned* bar  = (unsigned*)ws;
    float*    zb   = (float*)(ws + BAR);                         // 2 x 512 KB ping-pong
    u16*      rTu  = (u16*)(ws + BAR + 2 * 524288);              // 512 KB split state
    u16*      WiTu = (u16*)(ws + BAR + 2 * 524288 + 524288);     // 4 MB split Wi^T
    u16*      Ybf  = (u16*)(ws + BAR + 2 * 524288 + 524288 + 4194304); // 128 MB

    static int smem_set = 0;
    if (!smem_set) {
        hipFuncSetAttribute((const void*)rnn_persistent,
                            hipFuncAttributeMaxDynamicSharedMemorySize, 135168);
        smem_set = 1;
    }
    hipMemsetAsync(bar, 0, BAR, stream);
    rnn_persistent<<<256, 512, 135168, stream>>>(x, Win, Wr, out, rTu, zb, Ybf, WiTu, bar);
}

// Round 9
// 7365.723 us; speedup vs baseline: 1.0920x; 1.0920x over previous
//
#include <hip/hip_runtime.h>

#define NSTEP 512
#define EDIM  512
#define REC   2048
#define NB    64
#define KSEL  819
#define KC    8       // K chunks of 256 (kc = bid & 7)
#define ZCH   256     // K per block
#define AP    264     // padded k-stride (u16) for LDS tiles
#define CSTR  16896   // 64*AP: component stride inside LDS tiles
#define WITC  1048576 // u16 elems per WiT component (2048*512)

typedef unsigned short u16;
typedef __bf16 bf16x8 __attribute__((ext_vector_type(8)));
typedef float  f32x4  __attribute__((ext_vector_type(4)));
typedef unsigned long long ull;

static __device__ __forceinline__ f32x4 mfma16(bf16x8 a, bf16x8 b, f32x4 c) {
    return __builtin_amdgcn_mfma_f32_16x16x32_bf16(a, b, c, 0, 0, 0);
}

// fp32 -> 2 bf16 components (hi, lo): ~17 mantissa bits
static __device__ __forceinline__ void split2(float v, u16& c0, u16& c1) {
    __bf16 b0 = (__bf16)v;
    __bf16 b1 = (__bf16)(v - (float)b0);
    c0 = __builtin_bit_cast(u16, b0);
    c1 = __builtin_bit_cast(u16, b1);
}

// ---- agent-scope (sc1) coherent helpers — compiler-tracked ----
static __device__ __forceinline__ void cstore4f(float* p, float v) {
    __hip_atomic_store((unsigned*)p, __float_as_uint(v), __ATOMIC_RELAXED, __HIP_MEMORY_SCOPE_AGENT);
}
static __device__ __forceinline__ void cstore4u(unsigned* p, unsigned v) {
    __hip_atomic_store(p, v, __ATOMIC_RELAXED, __HIP_MEMORY_SCOPE_AGENT);
}
static __device__ __forceinline__ unsigned cload4u(const unsigned* p) {
    return __hip_atomic_load(p, __ATOMIC_RELAXED, __HIP_MEMORY_SCOPE_AGENT);
}
static __device__ __forceinline__ void cstore8u(void* p, ull v) {
    __hip_atomic_store((ull*)p, v, __ATOMIC_RELAXED, __HIP_MEMORY_SCOPE_AGENT);
}
static __device__ __forceinline__ ull cload8u(const void* p) {
    return __hip_atomic_load((const ull*)p, __ATOMIC_RELAXED, __HIP_MEMORY_SCOPE_AGENT);
}
static __device__ __forceinline__ float2 cload8f(const float* p) {
    ull u = cload8u(p);
    float2 v; __builtin_memcpy(&v, &u, 8);
    return v;
}

// ---------------------------------------------------------------------------
// Barriers (R6-proven). bar layout (uints):
//   arriveA[0..255] | arriveB[512..575] | releaseA[1024+g*32] | releaseB[1536+g*32]
//   ncnt[nc] at [2048 + nc*32], nc<32 — per-column-chunk z-ready counters
// ---------------------------------------------------------------------------
__device__ __forceinline__ void gbarA(unsigned* bar, int bid, int tid,
                                      unsigned gen, bool wait)
{
    __syncthreads();                               // drain block stores
    if (tid == 0) cstore4u(&bar[bid], gen);        // arrive
    if (bid == 0 && tid < 64) {                    // leader wave: parallel poll
        const ull* sl = (const ull*)bar;           // 128 ulls = 256 slots
        for (;;) {
            const ull v0 = cload8u(&sl[tid * 2]);
            const ull v1 = cload8u(&sl[tid * 2 + 1]);
            const bool ok = ((unsigned)v0 >= gen) && ((unsigned)(v0 >> 32) >= gen)
                         && ((unsigned)v1 >= gen) && ((unsigned)(v1 >> 32) >= gen);
            if (__all(ok)) break;
            __builtin_amdgcn_s_sleep(1);
        }
        if (tid < 16) cstore4u(&bar[1024 + tid * 32], gen);
    }
    if (wait) {
        if (tid == 0) {
            const int g = bid >> 4;
            while (cload4u(&bar[1024 + g * 32]) < gen)
                __builtin_amdgcn_s_sleep(1);
            __asm__ volatile("" ::: "memory");
        }
        __syncthreads();
    }
}

__device__ __forceinline__ void gbarB(unsigned* bar, int bid, int tid, unsigned gen)
{
    __syncthreads();                               // drain (phase-B r stores)
    if (bid < NB && tid == 0) cstore4u(&bar[512 + bid], gen);
    if (bid == 0 && tid < 64) {                    // leader wave: 1 slot/lane
        for (;;) {
            const unsigned v = cload4u(&bar[512 + tid]);
            if (__all(v >= gen)) break;
            __builtin_amdgcn_s_sleep(1);
        }
        if (tid < 16) cstore4u(&bar[1536 + tid * 32], gen);
    }
    if (tid == 0) {
        const int g = bid >> 4;
        while (cload4u(&bar[1536 + g * 32]) < gen)
            __builtin_amdgcn_s_sleep(1);
        __asm__ volatile("" ::: "memory");
    }
    __syncthreads();
}

// ---------------------------------------------------------------------------
// Persistent kernel: 256 blocks x 512 threads. R6 structure (z atomics into
// zb ping-pong, rTu split state, per-nc ncnt z-ready counters, leader barB,
// MFMA Y precompute, candidate-list tail) + radix-select LDS-conflict fix:
// 16 per-half-wave histograms (was 8 per-wave) and per-thread dedup of the
// clustered exponent bytes before pass-1 atomics. Selection bit-identical.
// Init gens: 1 = WiT done, 2 = Y+init done. ncnt target: 8*(t+1).
// barB gen: t+1.
// ---------------------------------------------------------------------------
__global__ __launch_bounds__(512, 1)
void rnn_persistent(const float* __restrict__ x, const float* __restrict__ Wi,
                    const float* __restrict__ Wr, float* __restrict__ out,
                    u16* __restrict__ rTu, float* __restrict__ zb,
                    u16* __restrict__ Ybf, u16* __restrict__ WiTu,
                    unsigned* __restrict__ bar)
{
    extern __shared__ __align__(16) char smem[];
    u16* WrSu = (u16*)smem;                         // + c*CSTR
    u16* aSu  = (u16*)(smem + 67584);               // + c*CSTR
    // transpose view (aliases WrSu region, used only pre-gen1)
    float* tp = (float*)smem;                       // [64][65] 16.6 KB
    // phase-B views (alias aS region)
    unsigned*      kS    = (unsigned*)(smem + 67584);            // [2048] 8 KB
    unsigned char* selS  = (unsigned char*)(smem + 67584 + 8192);// 2 KB
    unsigned*      hist  = (unsigned*)(smem + 67584 + 10240);    // [16][256] 16 KB
    __shared__ unsigned s_byte, s_newrem, s_cnteq;
    __shared__ float red[8];

    const int bid = blockIdx.x;
    const int tid = threadIdx.x;
    const int kc = bid & 7, nc = bid >> 3;
    const int n0 = nc * 64, kcbase = kc * ZCH;
    const int wid = tid >> 6, lane = tid & 63;
    const int q = lane >> 4, l16 = lane & 15;
    const int Moff = (wid & 3) * 16, Npair = wid >> 2;
    const bool isB = (bid < NB);
    unsigned* ncnt = &bar[2048];                    // + nc*32

    // ============ Phase 0: split-Wi^T transpose (one 64x64 tile/block) ======
    {
        const int jt = bid & 31, et = bid >> 5;
        const int j0 = jt * 64, e0 = et * 64;
        const int rr = tid >> 6, ln = tid & 63;
#pragma unroll
        for (int k = 0; k < 8; ++k) {
            const int r = k * 8 + rr;
            tp[r * 65 + ln] = Wi[(long long)(e0 + r) * REC + j0 + ln];
        }
        __syncthreads();
        const int c = tid >> 3, e8 = (tid & 7) * 8;
        u16 h[8], l[8];
#pragma unroll
        for (int i = 0; i < 8; ++i) split2(tp[(e8 + i) * 65 + c], h[i], l[i]);
        ull ph0, ph1, pl0, pl1;
        __builtin_memcpy(&ph0, &h[0], 8); __builtin_memcpy(&ph1, &h[4], 8);
        __builtin_memcpy(&pl0, &l[0], 8); __builtin_memcpy(&pl1, &l[4], 8);
        const long long bI = (long long)(j0 + c) * 512 + e0 + e8;
        cstore8u(&WiTu[bI], ph0);        cstore8u(&WiTu[bI + 4], ph1);
        cstore8u(&WiTu[WITC + bI], pl0); cstore8u(&WiTu[WITC + bI + 4], pl1);
    }
    gbarA(bar, bid, tid, 1u, true);

    // ============ Phase 1: Y[t][b][j] = (x_t @ Wi) via split-bf16 MFMA ======
    {
        const int t0 = bid * 2;
        for (int jc = 0; jc < 32; ++jc) {
            const int j0y = jc * 64;
            f32x4 aY[2][2];
#pragma unroll
            for (int tt = 0; tt < 2; ++tt)
#pragma unroll
                for (int i = 0; i < 2; ++i) aY[tt][i] = (f32x4){0,0,0,0};
            for (int kc2 = 0; kc2 < 2; ++kc2) {
                __syncthreads();                    // prior GEMM reads done
                // ---- stage B: WiT[j0y..+64][kc2*256..+256], both comps ----
#pragma unroll
                for (int i = 0; i < 8; ++i) {
                    const int chunk = i * 512 + tid;        // 4096 x 16B
                    const int cc = chunk >> 11;
                    const int jj = (chunk & 2047) >> 5;
                    const int e8 = chunk & 31;
                    const u16* src = WiTu + (long long)cc * WITC
                                   + (long long)(j0y + jj) * 512 + kc2 * 256 + e8 * 8;
                    const ull w0 = *(const ull*)src;
                    const ull w1 = *(const ull*)(src + 4);
                    u16* dst = WrSu + cc * CSTR + jj * AP + e8 * 8;
                    *(ull*)dst = w0;
                    *(ull*)(dst + 4) = w1;
                }
#pragma unroll
                for (int tt = 0; tt < 2; ++tt) {
                    __syncthreads();                // B staged / prev GEMM done
                    // ---- stage A: x[t][b][kc2*256..+256] split ----
#pragma unroll
                    for (int it = 0; it < 8; ++it) {
                        const int b = it * 8 + wid;
                        const float4 v = *(const float4*)(x
                            + ((long long)b * NSTEP + (t0 + tt)) * EDIM
                            + kc2 * 256 + lane * 4);
                        u16 hh[4], ll[4];
                        split2(v.x, hh[0], ll[0]); split2(v.y, hh[1], ll[1]);
                        split2(v.z, hh[2], ll[2]); split2(v.w, hh[3], ll[3]);
                        ull ph, pl;
                        __builtin_memcpy(&ph, hh, 8); __builtin_memcpy(&pl, ll, 8);
                        *(ull*)&aSu[b * AP + lane * 4] = ph;
                        *(ull*)&aSu[CSTR + b * AP + lane * 4] = pl;
                    }
                    __syncthreads();
                    f32x4 a0 = aY[tt][0], a1 = aY[tt][1];
#pragma unroll
                    for (int ks = 0; ks < 8; ++ks) {
                        const int kk = ks * 32 + q * 8;
                        const u16* ap = aSu + (Moff + l16) * AP + kk;
                        bf16x8 A0 = *(const bf16x8*)(ap);
                        bf16x8 A1 = *(const bf16x8*)(ap + CSTR);
                        const u16* bp0 = WrSu + (Npair * 32 + l16) * AP + kk;
                        bf16x8 B00 = *(const bf16x8*)(bp0);
                        bf16x8 B01 = *(const bf16x8*)(bp0 + CSTR);
                        const u16* bp1 = bp0 + 16 * AP;
                        bf16x8 B10 = *(const bf16x8*)(bp1);
                        bf16x8 B11 = *(const bf16x8*)(bp1 + CSTR);
                        a0 = mfma16(A0, B00, a0);
                        a1 = mfma16(A0, B10, a1);
                        a0 = mfma16(A0, B01, a0);
                        a1 = mfma16(A0, B11, a1);
                        a0 = mfma16(A1, B00, a0);
                        a1 = mfma16(A1, B10, a1);
                    }
                    aY[tt][0] = a0; aY[tt][1] = a1;
                }
            }
            // ---- epilogue: bf16-round, lane-pair pack, agent 4B stores ----
            const int jb = j0y + Npair * 32 + l16;
#pragma unroll
            for (int tt = 0; tt < 2; ++tt)
#pragma unroll
                for (int i = 0; i < 4; ++i) {
                    const int row = Moff + q * 4 + i;
                    const unsigned w0 = (unsigned)__builtin_bit_cast(u16, (__bf16)((float*)&aY[tt][0])[i]);
                    const unsigned w1 = (unsigned)__builtin_bit_cast(u16, (__bf16)((float*)&aY[tt][1])[i]);
                    const unsigned o0 = (unsigned)__shfl_xor((int)w0, 1);
                    const unsigned o1 = (unsigned)__shfl_xor((int)w1, 1);
                    if ((lane & 1) == 0) {
                        const long long yb = ((long long)(t0 + tt) * 64 + row) * REC + jb;
                        cstore4u((unsigned*)&Ybf[yb],      w0 | (o0 << 16));
                        cstore4u((unsigned*)&Ybf[yb + 16], w1 | (o1 << 16));
                    }
                }
        }
    }
    // ---- init: zero r slot (512 KB) and zb[0] (512 KB) ----
    {
        const int g = bid * 512 + tid;                  // 0..131071
        if (g < 65536) cstore8u(rTu + (long long)g * 4, 0ull);
        cstore4f(zb + g, 0.f);
    }
    gbarA(bar, bid, tid, 2u, true);

    // ================= one-time: stage + split Wr tile into LDS =============
    {
        for (int it = 0; it < 32; ++it) {
            const int row = it * 8 + wid;
            const int col = lane;
            const float v = Wr[(long long)(kcbase + row) * REC + n0 + col];
            u16 s0, s1; split2(v, s0, s1);
            const int base = col * AP + row;
            WrSu[base] = s0;
            WrSu[CSTR + base] = s1;
        }
        __syncthreads();
    }

    // ================= main recurrence ======================================
    const int hw = tid >> 5, hl = tid & 31;
    for (int t = 0; t < NSTEP; ++t) {
        float* zcur = zb + (size_t)(t & 1) * 131072;
        float* znxt = zb + (size_t)((t + 1) & 1) * 131072;
        // zero next-parity z (early, hides latency)
        cstore4f(znxt + bid * 512 + tid, 0.f);
        // ---- stage aS: 2 comps x 64 b x 256 k, sc1 8B ----
        {
            ull va[8], vbv[8];
#pragma unroll
            for (int i = 0; i < 8; ++i) {
                const int c = i >> 2;
                const int b = (i & 3) * 16 + hw;
                const u16* src = rTu + (long long)c * 131072 + (long long)b * REC + kcbase + hl * 8;
                va[i] = cload8u(src);
                vbv[i] = cload8u(src + 4);
            }
#pragma unroll
            for (int i = 0; i < 8; ++i) {
                const int c = i >> 2;
                const int b = (i & 3) * 16 + hw;
                u16* dst = aSu + c * CSTR + b * AP + hl * 8;
                *(ull*)dst = va[i];
                *(ull*)(dst + 4) = vbv[i];
            }
        }
        __syncthreads();

        // Y prefetch for phase B — issued early, completes under GEMM
        ushort4 yv;
        if (isB) yv = *(const ushort4*)&Ybf[((long long)t * 64 + bid) * REC + tid * 4];

        // ---- z tile: 3-pass split-bf16 MFMA, K=256 ----
        f32x4 acc0 = {0,0,0,0}, acc1 = {0,0,0,0};
#pragma unroll
        for (int ks = 0; ks < 8; ++ks) {
            const int kk = ks * 32 + q * 8;
            const u16* ap = aSu + (Moff + l16) * AP + kk;
            bf16x8 A0 = *(const bf16x8*)(ap);
            bf16x8 A1 = *(const bf16x8*)(ap + CSTR);
            const u16* bp0 = WrSu + (Npair * 32 + l16) * AP + kk;
            bf16x8 B00 = *(const bf16x8*)(bp0);
            bf16x8 B01 = *(const bf16x8*)(bp0 + CSTR);
            const u16* bp1 = bp0 + 16 * AP;
            bf16x8 B10 = *(const bf16x8*)(bp1);
            bf16x8 B11 = *(const bf16x8*)(bp1 + CSTR);
            acc0 = mfma16(A0, B00, acc0);
            acc1 = mfma16(A0, B10, acc1);
            acc0 = mfma16(A0, B01, acc0);
            acc1 = mfma16(A0, B11, acc1);
            acc0 = mfma16(A1, B00, acc0);
            acc1 = mfma16(A1, B10, acc1);
        }
        // ---- accumulate into z via HW f32 atomics ----
        {
            const int colA = n0 + Npair * 32 + l16;
#pragma unroll
            for (int i = 0; i < 4; ++i) {
                float* zp = zcur + (long long)(Moff + q * 4 + i) * REC + colA;
                unsafeAtomicAdd(zp,      ((float*)&acc0)[i]);
                unsafeAtomicAdd(zp + 16, ((float*)&acc1)[i]);
            }
        }
        // ---- per-nc arrival: syncthreads drains z atomics, then 1 add ----
        __syncthreads();
        if (tid == 0) atomicAdd(&ncnt[nc << 5], 1u);

        // ================= phase B: blocks 0..63, one batch row each ========
        if (isB) {
            const int b = bid;
            const int j0 = tid * 4;
            // wait only for the 8 kc-blocks of THIS thread's column chunk
            {
                const unsigned tgt = 8u * (unsigned)(t + 1);
                const unsigned* myc = &ncnt[(tid >> 4) << 5];
                while (cload4u(myc) < tgt) __builtin_amdgcn_s_sleep(1);
                __asm__ volatile("" ::: "memory");
            }
            float zs[4];
            {
                const float2 u0 = cload8f(zcur + (long long)b * REC + j0);
                const float2 u1 = cload8f(zcur + (long long)b * REC + j0 + 2);
                zs[0] = u0.x; zs[1] = u0.y; zs[2] = u1.x; zs[3] = u1.y;
            }
            unsigned kv[4];
#pragma unroll
            for (int s = 0; s < 4; ++s) {
                const unsigned u = __float_as_uint(zs[s]);
                kv[s] = (u & 0x80000000u) ? ~u : (u | 0x80000000u);
            }
            // ---- radix select: 16 half-wave histos + dedup'd pass-1 ----
            unsigned* hw_ = hist + (wid * 2 + (lane >> 5)) * 256;
            unsigned prefix = 0, remaining = KSEL;
            int done = 0;
            unsigned char sel[4];
            int sel_set = 0;
            for (int byte = 3; byte >= 0 && !done; --byte) {
                {   // zero all 16 copies: 512 threads x 8 entries
                    uint4 zz = {0u, 0u, 0u, 0u};
                    *(uint4*)&hist[tid * 8] = zz;
                    *(uint4*)&hist[tid * 8 + 4] = zz;
                }
                const int shift = byte * 8;
                if (byte == 3) {
                    // clustered exponent bytes: dedup within thread first
                    unsigned bb[4];
#pragma unroll
                    for (int s = 0; s < 4; ++s) bb[s] = kv[s] >> 24;
#pragma unroll
                    for (int s = 0; s < 4; ++s) {
                        bool first = true; unsigned cnt = 1u;
#pragma unroll
                        for (int s2 = 0; s2 < 4; ++s2) {
                            if (s2 < s && bb[s2] == bb[s]) first = false;
                            if (s2 > s && bb[s2] == bb[s]) ++cnt;
                        }
                        if (first) atomicAdd(&hw_[bb[s]], cnt);
                    }
                } else {
                    const unsigned pmask = 0xFFFFFFFFu << (shift + 8);
#pragma unroll
                    for (int s = 0; s < 4; ++s) {
                        if ((kv[s] & pmask) == prefix)
                            atomicAdd(&hw_[(kv[s] >> shift) & 255u], 1u);
                    }
                }
                __syncthreads();
                if (tid < 64) {   // wave 0: combine 16 copies + suffix scan
                    unsigned c0 = 0, c1 = 0, c2 = 0, c3 = 0;
#pragma unroll
                    for (int w = 0; w < 16; ++w) {
                        const uint4 hv = *(const uint4*)&hist[w * 256 + tid * 4];
                        c0 += hv.x; c1 += hv.y; c2 += hv.z; c3 += hv.w;
                    }
                    const unsigned tot = c0 + c1 + c2 + c3;
                    unsigned suf = tot;
#pragma unroll
                    for (int st = 1; st < 64; st <<= 1) {
                        unsigned o = __shfl_down(suf, (unsigned)st);
                        if (tid + st >= 64) o = 0u;
                        suf += o;
                    }
                    unsigned S[5];
                    S[0] = suf; S[1] = suf - c0; S[2] = suf - c0 - c1;
                    S[3] = suf - c0 - c1 - c2; S[4] = suf - tot;
                    const unsigned cc[4] = {c0, c1, c2, c3};
#pragma unroll
                    for (int qq = 0; qq < 4; ++qq) {
                        if (S[qq] >= remaining && S[qq + 1] < remaining) {
                            s_byte = (unsigned)(tid * 4 + qq);
                            s_newrem = remaining - S[qq + 1];
                            s_cnteq = cc[qq];
                        }
                    }
                }
                __syncthreads();
                prefix |= (s_byte << shift);
                remaining = s_newrem;
                if (remaining == s_cnteq) { done = 1; continue; }
                // ---- candidate-list tail: pivot bucket small -> rank directly
                if (s_cnteq <= 64u) {
                    const unsigned maskk = 0xFFFFFFFFu << shift;
                    if (tid == 0) kS[128] = 0u;
                    *(unsigned*)&selS[j0] = 0u;
                    __syncthreads();
#pragma unroll
                    for (int s = 0; s < 4; ++s) {
                        if ((kv[s] & maskk) == prefix) {
                            const unsigned p = atomicAdd(&kS[128], 1u);
                            kS[p] = kv[s];
                            kS[64 + p] = (unsigned)(j0 + s);
                        }
                    }
                    __syncthreads();
                    if (tid < 64) {
                        const unsigned cnt = kS[128];
                        if ((unsigned)lane < cnt) {
                            const unsigned myK = kS[lane];
                            const unsigned myI = kS[64 + lane];
                            unsigned rank = 0;
                            for (unsigned j = 0; j < cnt; ++j) {
                                const unsigned bk = kS[j], bi = kS[64 + j];
                                if (bk > myK || (bk == myK && bi < myI)) ++rank;
                            }
                            if (rank < remaining) selS[myI] = 1;
                        }
                    }
                    __syncthreads();
#pragma unroll
                    for (int s = 0; s < 4; ++s) {
                        const unsigned m = kv[s] & maskk;
                        sel[s] = (m > prefix) ? 1 : ((m == prefix) ? selS[j0 + s] : 0);
                    }
                    sel_set = 1;
                    break;
                }
            }
            if (!sel_set) {
                if (done) {
#pragma unroll
                    for (int s = 0; s < 4; ++s)
                        sel[s] = (kv[s] >= prefix) ? 1 : 0;
                } else {
                    // tie at exact threshold with >64 dups (step 0: all-zero z).
                    *(uint4*)&kS[j0] = *(uint4*)kv;
                    __syncthreads();
                    if (tid == 0) {
                        unsigned rem = remaining;
                        const unsigned T = prefix;
                        for (int j = 0; j < REC; ++j) {
                            const unsigned k = kS[j];
                            unsigned char sl = 0;
                            if (k > T) sl = 1;
                            else if (k == T && rem > 0u) { sl = 1; --rem; }
                            selS[j] = sl;
                        }
                    }
                    __syncthreads();
#pragma unroll
                    for (int s = 0; s < 4; ++s) sel[s] = selS[j0 + s];
                }
            }
            // ---- r_new = tanh(y + masked z), row-normalize ----
            float rn[4]; float ss = 0.f;
            const u16 ya[4] = {yv.x, yv.y, yv.z, yv.w};
#pragma unroll
            for (int s = 0; s < 4; ++s) {
                const float y = __uint_as_float(((unsigned)ya[s]) << 16);
                const float v = y + (sel[s] ? zs[s] : 0.f);
                const float th = tanhf(v);
                rn[s] = th; ss += th * th;
            }
#pragma unroll
            for (int off = 32; off > 0; off >>= 1)
                ss += __shfl_down(ss, (unsigned)off);
            if (lane == 0) red[wid] = ss;
            __syncthreads();
            float a = 0.f;
#pragma unroll
            for (int i = 0; i < 8; ++i) a += red[i];
            const float inv = 1.0f / (sqrtf(a) + 1e-6f);
            u16 o0[4], o1[4];
            float4 ov;
#pragma unroll
            for (int s = 0; s < 4; ++s) {
                const float v = rn[s] * inv;
                split2(v, o0[s], o1[s]);
                ((float*)&ov)[s] = v;
            }
            ull p0, p1;
            __builtin_memcpy(&p0, o0, 8); __builtin_memcpy(&p1, o1, 8);
            cstore8u(rTu + (long long)b * REC + j0, p0);
            cstore8u(rTu + 131072 + (long long)b * REC + j0, p1);
            if (t == NSTEP - 1)
                *(float4*)&out[(long long)b * REC + j0] = ov;
        }
        // bar2: phase-B blocks arrive; everyone waits (r ready)
        gbarB(bar, bid, tid, (unsigned)(t + 1));
    }
}

// ---------------------------------------------------------------------------
extern "C" void kernel_launch(void* const* d_in, const int* in_sizes, int n_in,
                              void* d_out, int out_size, void* d_ws, size_t ws_size,
                              hipStream_t stream)
{
    const float* x   = (const float*)d_in[0];   // [64][512][512]
    const float* Win = (const float*)d_in[1];   // [512][2048]
    const float* Wr  = (const float*)d_in[2];   // [2048][2048]
    float* out = (float*)d_out;                 // [64][2048]

    char* ws = (char*)d_ws;
    const size_t BAR = 16384;                   // includes ncnt[32] lines
    unsigned* bar  = (unsigned*)ws;
    float*    zb   = (float*)(ws + BAR);                         // 2 x 512 KB ping-pong
    u16*      rTu  = (u16*)(ws + BAR + 2 * 524288);              // 512 KB split state
    u16*      WiTu = (u16*)(ws + BAR + 2 * 524288 + 524288);     // 4 MB split Wi^T
    u16*      Ybf  = (u16*)(ws + BAR + 2 * 524288 + 524288 + 4194304); // 128 MB

    static int smem_set = 0;
    if (!smem_set) {
        hipFuncSetAttribute((const void*)rnn_persistent,
                            hipFuncAttributeMaxDynamicSharedMemorySize, 135168);
        smem_set = 1;
    }
    hipMemsetAsync(bar, 0, BAR, stream);
    rnn_persistent<<<256, 512, 135168, stream>>>(x, Win, Wr, out, rTu, zb, Ybf, WiTu, bar);
}

// Round 10
// 7180.192 us; speedup vs baseline: 1.1202x; 1.0258x over previous
//
#include <hip/hip_runtime.h>

#define NSTEP 512
#define EDIM  512
#define REC   2048
#define NB    64
#define KSEL  819
#define KC    8       // K chunks of 256 (kc = bid & 7)
#define ZCH   256     // K per block
#define AP    264     // padded k-stride (u16) for LDS tiles
#define CSTR  16896   // 64*AP: component stride inside LDS tiles
#define WITC  1048576 // u16 elems per WiT component (2048*512)

typedef unsigned short u16;
typedef __bf16 bf16x8 __attribute__((ext_vector_type(8)));
typedef float  f32x4  __attribute__((ext_vector_type(4)));
typedef unsigned long long ull;

static __device__ __forceinline__ f32x4 mfma16(bf16x8 a, bf16x8 b, f32x4 c) {
    return __builtin_amdgcn_mfma_f32_16x16x32_bf16(a, b, c, 0, 0, 0);
}

// fp32 -> 2 bf16 components (hi, lo): ~17 mantissa bits
static __device__ __forceinline__ void split2(float v, u16& c0, u16& c1) {
    __bf16 b0 = (__bf16)v;
    __bf16 b1 = (__bf16)(v - (float)b0);
    c0 = __builtin_bit_cast(u16, b0);
    c1 = __builtin_bit_cast(u16, b1);
}

// ---- agent-scope (sc1) coherent helpers — compiler-tracked ----
static __device__ __forceinline__ void cstore4f(float* p, float v) {
    __hip_atomic_store((unsigned*)p, __float_as_uint(v), __ATOMIC_RELAXED, __HIP_MEMORY_SCOPE_AGENT);
}
static __device__ __forceinline__ void cstore4u(unsigned* p, unsigned v) {
    __hip_atomic_store(p, v, __ATOMIC_RELAXED, __HIP_MEMORY_SCOPE_AGENT);
}
static __device__ __forceinline__ unsigned cload4u(const unsigned* p) {
    return __hip_atomic_load(p, __ATOMIC_RELAXED, __HIP_MEMORY_SCOPE_AGENT);
}
static __device__ __forceinline__ void cstore8u(void* p, ull v) {
    __hip_atomic_store((ull*)p, v, __ATOMIC_RELAXED, __HIP_MEMORY_SCOPE_AGENT);
}
static __device__ __forceinline__ ull cload8u(const void* p) {
    return __hip_atomic_load((const ull*)p, __ATOMIC_RELAXED, __HIP_MEMORY_SCOPE_AGENT);
}
static __device__ __forceinline__ float2 cload8f(const float* p) {
    ull u = cload8u(p);
    float2 v; __builtin_memcpy(&v, &u, 8);
    return v;
}

// ---------------------------------------------------------------------------
// Barriers. bar layout (uints):
//   arriveA[0..255] | arriveB[512..575] | releaseA[1024+g*32] | releaseB[1536+g*32]
//   ncnt[nc] at [2048 + nc*32], nc<32 (one 128B line each) — per-column-chunk
//   arrival counters for the main-loop z dependency (replaces barA there).
// Leader barriers (init + barB): R0-proven fan-in topology. Topology law from
// R1/R2/R4/R8: distinct-address fan-in + parallel leader poll beats shared
// counters and mass direct-polling; keep pollers-per-line <= ~16.
// ---------------------------------------------------------------------------
__device__ __forceinline__ void gbarA(unsigned* bar, int bid, int tid,
                                      unsigned gen, bool wait)
{
    __syncthreads();                               // drain block stores
    if (tid == 0) cstore4u(&bar[bid], gen);        // arrive
    if (bid == 0 && tid < 64) {                    // leader wave: parallel poll
        const ull* sl = (const ull*)bar;           // 128 ulls = 256 slots
        for (;;) {
            const ull v0 = cload8u(&sl[tid * 2]);
            const ull v1 = cload8u(&sl[tid * 2 + 1]);
            const bool ok = ((unsigned)v0 >= gen) && ((unsigned)(v0 >> 32) >= gen)
                         && ((unsigned)v1 >= gen) && ((unsigned)(v1 >> 32) >= gen);
            if (__all(ok)) break;
            __builtin_amdgcn_s_sleep(1);
        }
        if (tid < 16) cstore4u(&bar[1024 + tid * 32], gen);
    }
    if (wait) {
        if (tid == 0) {
            const int g = bid >> 4;
            while (cload4u(&bar[1024 + g * 32]) < gen)
                __builtin_amdgcn_s_sleep(1);
            __asm__ volatile("" ::: "memory");
        }
        __syncthreads();
    }
}

__device__ __forceinline__ void gbarB(unsigned* bar, int bid, int tid, unsigned gen)
{
    __syncthreads();                               // drain (phase-B r stores)
    if (bid < NB && tid == 0) cstore4u(&bar[512 + bid], gen);
    if (bid == 0 && tid < 64) {                    // leader wave: 1 slot/lane
        for (;;) {
            const unsigned v = cload4u(&bar[512 + tid]);
            if (__all(v >= gen)) break;
            __builtin_amdgcn_s_sleep(1);
        }
        if (tid < 16) cstore4u(&bar[1536 + tid * 32], gen);
    }
    if (tid == 0) {
        const int g = bid >> 4;
        while (cload4u(&bar[1536 + g * 32]) < gen)
            __builtin_amdgcn_s_sleep(1);
        __asm__ volatile("" ::: "memory");
    }
    __syncthreads();
}

// ---------------------------------------------------------------------------
// Persistent kernel: 256 blocks x 512 threads. Best verified configuration
// (R6, 7182 us): z via HW f32 atomics into zb ping-pong, rTu split state,
// per-nc ncnt z-ready counters (8-fan-in), leader barB, MFMA split-bf16 Y
// precompute, candidate-list select tail, 8 per-wave histograms.
// Init gens: 1 = WiT done, 2 = Y+init done. ncnt target: 8*(t+1).
// barB gen: t+1.
// ---------------------------------------------------------------------------
__global__ __launch_bounds__(512, 1)
void rnn_persistent(const float* __restrict__ x, const float* __restrict__ Wi,
                    const float* __restrict__ Wr, float* __restrict__ out,
                    u16* __restrict__ rTu, float* __restrict__ zb,
                    u16* __restrict__ Ybf, u16* __restrict__ WiTu,
                    unsigned* __restrict__ bar)
{
    extern __shared__ __align__(16) char smem[];
    u16* WrSu = (u16*)smem;                         // + c*CSTR
    u16* aSu  = (u16*)(smem + 67584);               // + c*CSTR
    // transpose view (aliases WrSu region, used only pre-gen1)
    float* tp = (float*)smem;                       // [64][65] 16.6 KB
    // phase-B views (alias aS region)
    unsigned*      kS    = (unsigned*)(smem + 67584);            // [2048] 8 KB
    unsigned char* selS  = (unsigned char*)(smem + 67584 + 8192);// 2 KB
    unsigned*      hist  = (unsigned*)(smem + 67584 + 10240);    // [8][256] 8 KB
    __shared__ unsigned s_byte, s_newrem, s_cnteq;
    __shared__ float red[8];

    const int bid = blockIdx.x;
    const int tid = threadIdx.x;
    const int kc = bid & 7, nc = bid >> 3;
    const int n0 = nc * 64, kcbase = kc * ZCH;
    const int wid = tid >> 6, lane = tid & 63;
    const int q = lane >> 4, l16 = lane & 15;
    const int Moff = (wid & 3) * 16, Npair = wid >> 2;
    const bool isB = (bid < NB);
    unsigned* ncnt = &bar[2048];                    // + nc*32

    // ============ Phase 0: split-Wi^T transpose (one 64x64 tile/block) ======
    {
        const int jt = bid & 31, et = bid >> 5;
        const int j0 = jt * 64, e0 = et * 64;
        const int rr = tid >> 6, ln = tid & 63;
#pragma unroll
        for (int k = 0; k < 8; ++k) {
            const int r = k * 8 + rr;
            tp[r * 65 + ln] = Wi[(long long)(e0 + r) * REC + j0 + ln];
        }
        __syncthreads();
        const int c = tid >> 3, e8 = (tid & 7) * 8;
        u16 h[8], l[8];
#pragma unroll
        for (int i = 0; i < 8; ++i) split2(tp[(e8 + i) * 65 + c], h[i], l[i]);
        ull ph0, ph1, pl0, pl1;
        __builtin_memcpy(&ph0, &h[0], 8); __builtin_memcpy(&ph1, &h[4], 8);
        __builtin_memcpy(&pl0, &l[0], 8); __builtin_memcpy(&pl1, &l[4], 8);
        const long long bI = (long long)(j0 + c) * 512 + e0 + e8;
        cstore8u(&WiTu[bI], ph0);        cstore8u(&WiTu[bI + 4], ph1);
        cstore8u(&WiTu[WITC + bI], pl0); cstore8u(&WiTu[WITC + bI + 4], pl1);
    }
    gbarA(bar, bid, tid, 1u, true);

    // ============ Phase 1: Y[t][b][j] = (x_t @ Wi) via split-bf16 MFMA ======
    {
        const int t0 = bid * 2;
        for (int jc = 0; jc < 32; ++jc) {
            const int j0y = jc * 64;
            f32x4 aY[2][2];
#pragma unroll
            for (int tt = 0; tt < 2; ++tt)
#pragma unroll
                for (int i = 0; i < 2; ++i) aY[tt][i] = (f32x4){0,0,0,0};
            for (int kc2 = 0; kc2 < 2; ++kc2) {
                __syncthreads();                    // prior GEMM reads done
                // ---- stage B: WiT[j0y..+64][kc2*256..+256], both comps ----
#pragma unroll
                for (int i = 0; i < 8; ++i) {
                    const int chunk = i * 512 + tid;        // 4096 x 16B
                    const int cc = chunk >> 11;
                    const int jj = (chunk & 2047) >> 5;
                    const int e8 = chunk & 31;
                    const u16* src = WiTu + (long long)cc * WITC
                                   + (long long)(j0y + jj) * 512 + kc2 * 256 + e8 * 8;
                    const ull w0 = *(const ull*)src;
                    const ull w1 = *(const ull*)(src + 4);
                    u16* dst = WrSu + cc * CSTR + jj * AP + e8 * 8;
                    *(ull*)dst = w0;
                    *(ull*)(dst + 4) = w1;
                }
#pragma unroll
                for (int tt = 0; tt < 2; ++tt) {
                    __syncthreads();                // B staged / prev GEMM done
                    // ---- stage A: x[t][b][kc2*256..+256] split ----
#pragma unroll
                    for (int it = 0; it < 8; ++it) {
                        const int b = it * 8 + wid;
                        const float4 v = *(const float4*)(x
                            + ((long long)b * NSTEP + (t0 + tt)) * EDIM
                            + kc2 * 256 + lane * 4);
                        u16 hh[4], ll[4];
                        split2(v.x, hh[0], ll[0]); split2(v.y, hh[1], ll[1]);
                        split2(v.z, hh[2], ll[2]); split2(v.w, hh[3], ll[3]);
                        ull ph, pl;
                        __builtin_memcpy(&ph, hh, 8); __builtin_memcpy(&pl, ll, 8);
                        *(ull*)&aSu[b * AP + lane * 4] = ph;
                        *(ull*)&aSu[CSTR + b * AP + lane * 4] = pl;
                    }
                    __syncthreads();
                    f32x4 a0 = aY[tt][0], a1 = aY[tt][1];
#pragma unroll
                    for (int ks = 0; ks < 8; ++ks) {
                        const int kk = ks * 32 + q * 8;
                        const u16* ap = aSu + (Moff + l16) * AP + kk;
                        bf16x8 A0 = *(const bf16x8*)(ap);
                        bf16x8 A1 = *(const bf16x8*)(ap + CSTR);
                        const u16* bp0 = WrSu + (Npair * 32 + l16) * AP + kk;
                        bf16x8 B00 = *(const bf16x8*)(bp0);
                        bf16x8 B01 = *(const bf16x8*)(bp0 + CSTR);
                        const u16* bp1 = bp0 + 16 * AP;
                        bf16x8 B10 = *(const bf16x8*)(bp1);
                        bf16x8 B11 = *(const bf16x8*)(bp1 + CSTR);
                        a0 = mfma16(A0, B00, a0);
                        a1 = mfma16(A0, B10, a1);
                        a0 = mfma16(A0, B01, a0);
                        a1 = mfma16(A0, B11, a1);
                        a0 = mfma16(A1, B00, a0);
                        a1 = mfma16(A1, B10, a1);
                    }
                    aY[tt][0] = a0; aY[tt][1] = a1;
                }
            }
            // ---- epilogue: bf16-round, lane-pair pack, agent 4B stores ----
            const int jb = j0y + Npair * 32 + l16;
#pragma unroll
            for (int tt = 0; tt < 2; ++tt)
#pragma unroll
                for (int i = 0; i < 4; ++i) {
                    const int row = Moff + q * 4 + i;
                    const unsigned w0 = (unsigned)__builtin_bit_cast(u16, (__bf16)((float*)&aY[tt][0])[i]);
                    const unsigned w1 = (unsigned)__builtin_bit_cast(u16, (__bf16)((float*)&aY[tt][1])[i]);
                    const unsigned o0 = (unsigned)__shfl_xor((int)w0, 1);
                    const unsigned o1 = (unsigned)__shfl_xor((int)w1, 1);
                    if ((lane & 1) == 0) {
                        const long long yb = ((long long)(t0 + tt) * 64 + row) * REC + jb;
                        cstore4u((unsigned*)&Ybf[yb],      w0 | (o0 << 16));
                        cstore4u((unsigned*)&Ybf[yb + 16], w1 | (o1 << 16));
                    }
                }
        }
    }
    // ---- init: zero r slot (512 KB) and zb[0] (512 KB) ----
    {
        const int g = bid * 512 + tid;                  // 0..131071
        if (g < 65536) cstore8u(rTu + (long long)g * 4, 0ull);
        cstore4f(zb + g, 0.f);
    }
    gbarA(bar, bid, tid, 2u, true);

    // ================= one-time: stage + split Wr tile into LDS =============
    {
        for (int it = 0; it < 32; ++it) {
            const int row = it * 8 + wid;
            const int col = lane;
            const float v = Wr[(long long)(kcbase + row) * REC + n0 + col];
            u16 s0, s1; split2(v, s0, s1);
            const int base = col * AP + row;
            WrSu[base] = s0;
            WrSu[CSTR + base] = s1;
        }
        __syncthreads();
    }

    // ================= main recurrence ======================================
    const int hw = tid >> 5, hl = tid & 31;
    for (int t = 0; t < NSTEP; ++t) {
        float* zcur = zb + (size_t)(t & 1) * 131072;
        float* znxt = zb + (size_t)((t + 1) & 1) * 131072;
        // zero next-parity z (early, hides latency)
        cstore4f(znxt + bid * 512 + tid, 0.f);
        // ---- stage aS: 2 comps x 64 b x 256 k, sc1 8B ----
        {
            ull va[8], vbv[8];
#pragma unroll
            for (int i = 0; i < 8; ++i) {
                const int c = i >> 2;
                const int b = (i & 3) * 16 + hw;
                const u16* src = rTu + (long long)c * 131072 + (long long)b * REC + kcbase + hl * 8;
                va[i] = cload8u(src);
                vbv[i] = cload8u(src + 4);
            }
#pragma unroll
            for (int i = 0; i < 8; ++i) {
                const int c = i >> 2;
                const int b = (i & 3) * 16 + hw;
                u16* dst = aSu + c * CSTR + b * AP + hl * 8;
                *(ull*)dst = va[i];
                *(ull*)(dst + 4) = vbv[i];
            }
        }
        __syncthreads();

        // Y prefetch for phase B — issued early, completes under GEMM
        ushort4 yv;
        if (isB) yv = *(const ushort4*)&Ybf[((long long)t * 64 + bid) * REC + tid * 4];

        // ---- z tile: 3-pass split-bf16 MFMA, K=256 ----
        f32x4 acc0 = {0,0,0,0}, acc1 = {0,0,0,0};
#pragma unroll
        for (int ks = 0; ks < 8; ++ks) {
            const int kk = ks * 32 + q * 8;
            const u16* ap = aSu + (Moff + l16) * AP + kk;
            bf16x8 A0 = *(const bf16x8*)(ap);
            bf16x8 A1 = *(const bf16x8*)(ap + CSTR);
            const u16* bp0 = WrSu + (Npair * 32 + l16) * AP + kk;
            bf16x8 B00 = *(const bf16x8*)(bp0);
            bf16x8 B01 = *(const bf16x8*)(bp0 + CSTR);
            const u16* bp1 = bp0 + 16 * AP;
            bf16x8 B10 = *(const bf16x8*)(bp1);
            bf16x8 B11 = *(const bf16x8*)(bp1 + CSTR);
            acc0 = mfma16(A0, B00, acc0);
            acc1 = mfma16(A0, B10, acc1);
            acc0 = mfma16(A0, B01, acc0);
            acc1 = mfma16(A0, B11, acc1);
            acc0 = mfma16(A1, B00, acc0);
            acc1 = mfma16(A1, B10, acc1);
        }
        // ---- accumulate into z via HW f32 atomics ----
        {
            const int colA = n0 + Npair * 32 + l16;
#pragma unroll
            for (int i = 0; i < 4; ++i) {
                float* zp = zcur + (long long)(Moff + q * 4 + i) * REC + colA;
                unsafeAtomicAdd(zp,      ((float*)&acc0)[i]);
                unsafeAtomicAdd(zp + 16, ((float*)&acc1)[i]);
            }
        }
        // ---- per-nc arrival: syncthreads drains z atomics, then 1 add ----
        __syncthreads();
        if (tid == 0) atomicAdd(&ncnt[nc << 5], 1u);

        // ================= phase B: blocks 0..63, one batch row each ========
        if (isB) {
            const int b = bid;
            const int j0 = tid * 4;
            // wait only for the 8 kc-blocks of THIS thread's column chunk
            {
                const unsigned tgt = 8u * (unsigned)(t + 1);
                const unsigned* myc = &ncnt[(tid >> 4) << 5];
                while (cload4u(myc) < tgt) __builtin_amdgcn_s_sleep(1);
                __asm__ volatile("" ::: "memory");
            }
            float zs[4];
            {
                const float2 u0 = cload8f(zcur + (long long)b * REC + j0);
                const float2 u1 = cload8f(zcur + (long long)b * REC + j0 + 2);
                zs[0] = u0.x; zs[1] = u0.y; zs[2] = u1.x; zs[3] = u1.y;
            }
            unsigned kv[4];
#pragma unroll
            for (int s = 0; s < 4; ++s) {
                const unsigned u = __float_as_uint(zs[s]);
                kv[s] = (u & 0x80000000u) ? ~u : (u | 0x80000000u);
            }
            // ---- radix select w/ early exit + candidate-list tail ----
            unsigned* hw_ = hist + wid * 256;
            unsigned prefix = 0, remaining = KSEL;
            int done = 0;
            unsigned char sel[4];
            int sel_set = 0;
            for (int byte = 3; byte >= 0 && !done; --byte) {
                {
                    uint4 zz = {0u, 0u, 0u, 0u};
                    *(uint4*)&hw_[lane * 4] = zz;
                }
                const int shift = byte * 8;
                const unsigned pmask = (byte == 3) ? 0u : (0xFFFFFFFFu << (shift + 8));
#pragma unroll
                for (int s = 0; s < 4; ++s) {
                    if ((kv[s] & pmask) == prefix)
                        atomicAdd(&hw_[(kv[s] >> shift) & 255u], 1u);
                }
                __syncthreads();
                if (tid < 64) {   // wave 0: combine 8 copies + suffix scan
                    unsigned c0 = 0, c1 = 0, c2 = 0, c3 = 0;
#pragma unroll
                    for (int w = 0; w < 8; ++w) {
                        const uint4 hv = *(const uint4*)&hist[w * 256 + tid * 4];
                        c0 += hv.x; c1 += hv.y; c2 += hv.z; c3 += hv.w;
                    }
                    const unsigned tot = c0 + c1 + c2 + c3;
                    unsigned suf = tot;
#pragma unroll
                    for (int st = 1; st < 64; st <<= 1) {
                        unsigned o = __shfl_down(suf, (unsigned)st);
                        if (tid + st >= 64) o = 0u;
                        suf += o;
                    }
                    unsigned S[5];
                    S[0] = suf; S[1] = suf - c0; S[2] = suf - c0 - c1;
                    S[3] = suf - c0 - c1 - c2; S[4] = suf - tot;
                    const unsigned cc[4] = {c0, c1, c2, c3};
#pragma unroll
                    for (int qq = 0; qq < 4; ++qq) {
                        if (S[qq] >= remaining && S[qq + 1] < remaining) {
                            s_byte = (unsigned)(tid * 4 + qq);
                            s_newrem = remaining - S[qq + 1];
                            s_cnteq = cc[qq];
                        }
                    }
                }
                __syncthreads();
                prefix |= (s_byte << shift);
                remaining = s_newrem;
                if (remaining == s_cnteq) { done = 1; continue; }
                // ---- candidate-list tail: pivot bucket small -> rank directly
                if (s_cnteq <= 64u) {
                    const unsigned maskk = 0xFFFFFFFFu << shift;
                    if (tid == 0) kS[128] = 0u;
                    *(unsigned*)&selS[j0] = 0u;
                    __syncthreads();
#pragma unroll
                    for (int s = 0; s < 4; ++s) {
                        if ((kv[s] & maskk) == prefix) {
                            const unsigned p = atomicAdd(&kS[128], 1u);
                            kS[p] = kv[s];
                            kS[64 + p] = (unsigned)(j0 + s);
                        }
                    }
                    __syncthreads();
                    if (tid < 64) {
                        const unsigned cnt = kS[128];
                        if ((unsigned)lane < cnt) {
                            const unsigned myK = kS[lane];
                            const unsigned myI = kS[64 + lane];
                            unsigned rank = 0;
                            for (unsigned j = 0; j < cnt; ++j) {
                                const unsigned bk = kS[j], bi = kS[64 + j];
                                if (bk > myK || (bk == myK && bi < myI)) ++rank;
                            }
                            if (rank < remaining) selS[myI] = 1;
                        }
                    }
                    __syncthreads();
#pragma unroll
                    for (int s = 0; s < 4; ++s) {
                        const unsigned m = kv[s] & maskk;
                        sel[s] = (m > prefix) ? 1 : ((m == prefix) ? selS[j0 + s] : 0);
                    }
                    sel_set = 1;
                    break;
                }
            }
            if (!sel_set) {
                if (done) {
#pragma unroll
                    for (int s = 0; s < 4; ++s)
                        sel[s] = (kv[s] >= prefix) ? 1 : 0;
                } else {
                    // tie at exact threshold with >64 dups (step 0: all-zero z).
                    *(uint4*)&kS[j0] = *(uint4*)kv;
                    __syncthreads();
                    if (tid == 0) {
                        unsigned rem = remaining;
                        const unsigned T = prefix;
                        for (int j = 0; j < REC; ++j) {
                            const unsigned k = kS[j];
                            unsigned char sl = 0;
                            if (k > T) sl = 1;
                            else if (k == T && rem > 0u) { sl = 1; --rem; }
                            selS[j] = sl;
                        }
                    }
                    __syncthreads();
#pragma unroll
                    for (int s = 0; s < 4; ++s) sel[s] = selS[j0 + s];
                }
            }
            // ---- r_new = tanh(y + masked z), row-normalize ----
            float rn[4]; float ss = 0.f;
            const u16 ya[4] = {yv.x, yv.y, yv.z, yv.w};
#pragma unroll
            for (int s = 0; s < 4; ++s) {
                const float y = __uint_as_float(((unsigned)ya[s]) << 16);
                const float v = y + (sel[s] ? zs[s] : 0.f);
                const float th = tanhf(v);
                rn[s] = th; ss += th * th;
            }
#pragma unroll
            for (int off = 32; off > 0; off >>= 1)
                ss += __shfl_down(ss, (unsigned)off);
            if (lane == 0) red[wid] = ss;
            __syncthreads();
            float a = 0.f;
#pragma unroll
            for (int i = 0; i < 8; ++i) a += red[i];
            const float inv = 1.0f / (sqrtf(a) + 1e-6f);
            u16 o0[4], o1[4];
            float4 ov;
#pragma unroll
            for (int s = 0; s < 4; ++s) {
                const float v = rn[s] * inv;
                split2(v, o0[s], o1[s]);
                ((float*)&ov)[s] = v;
            }
            ull p0, p1;
            __builtin_memcpy(&p0, o0, 8); __builtin_memcpy(&p1, o1, 8);
            cstore8u(rTu + (long long)b * REC + j0, p0);
            cstore8u(rTu + 131072 + (long long)b * REC + j0, p1);
            if (t == NSTEP - 1)
                *(float4*)&out[(long long)b * REC + j0] = ov;
        }
        // bar2: phase-B blocks arrive; everyone waits (r ready)
        gbarB(bar, bid, tid, (unsigned)(t + 1));
    }
}

// ---------------------------------------------------------------------------
extern "C" void kernel_launch(void* const* d_in, const int* in_sizes, int n_in,
                              void* d_out, int out_size, void* d_ws, size_t ws_size,
                              hipStream_t stream)
{
    const float* x   = (const float*)d_in[0];   // [64][512][512]
    const float* Win = (const float*)d_in[1];   // [512][2048]
    const float* Wr  = (const float*)d_in[2];   // [2048][2048]
    float* out = (float*)d_out;                 // [64][2048]

    char* ws = (char*)d_ws;
    const size_t BAR = 16384;                   // includes ncnt[32] lines
    unsigned* bar  = (unsigned*)ws;
    float*    zb   = (float*)(ws + BAR);                         // 2 x 512 KB ping-pong
    u16*      rTu  = (u16*)(ws + BAR + 2 * 524288);              // 512 KB split state
    u16*      WiTu = (u16*)(ws + BAR + 2 * 524288 + 524288);     // 4 MB split Wi^T
    u16*      Ybf  = (u16*)(ws + BAR + 2 * 524288 + 524288 + 4194304); // 128 MB

    static int smem_set = 0;
    if (!smem_set) {
        hipFuncSetAttribute((const void*)rnn_persistent,
                            hipFuncAttributeMaxDynamicSharedMemorySize, 135168);
        smem_set = 1;
    }
    hipMemsetAsync(bar, 0, BAR, stream);
    rnn_persistent<<<256, 512, 135168, stream>>>(x, Win, Wr, out, rTu, zb, Ybf, WiTu, bar);
}